// Round 1
// baseline (1467.964 us; speedup 1.0000x reference)
//
#include <hip/hip_runtime.h>

// ---------------- deg init: deg[i] = 1 (self-loop) ----------------
__global__ void k_deg_init(int* __restrict__ deg, int n) {
    int i = blockIdx.x * blockDim.x + threadIdx.x;
    if (i < n) deg[i] = 1;
}

// ---------------- deg count: deg[col[e]] += 1 ----------------
__global__ void k_deg_count(const int* __restrict__ col, int* __restrict__ deg, int e) {
    int i = blockIdx.x * blockDim.x + threadIdx.x;
    if (i < e) atomicAdd(&deg[col[i]], 1);
}

// ---------------- fused dual GEMM + dinv + self-loop/bias init ----------------
// Per block: 64 rows of x. LDS: x tile + both W matrices.
// Each thread: lane d = output dim, group g handles 16 rows.
// Writes: dinv[r], y[r][d] = (x@Wc)[r][d]*dinv[r],
//         out[r][d] = (x@Ws)[r][d] + bs[d] + bc[d] + dinv[r]*y[r][d]
__global__ __launch_bounds__(256) void k_gemm(
    const float* __restrict__ x, const float* __restrict__ Wc,
    const float* __restrict__ bc, const float* __restrict__ Ws,
    const float* __restrict__ bs, const int* __restrict__ deg,
    float* __restrict__ dinv, float* __restrict__ y,
    float* __restrict__ out, int n)
{
    __shared__ float sWc[64 * 64];
    __shared__ float sWs[64 * 64];
    __shared__ float sx[64 * 64];
    const int t = threadIdx.x;

    // stage W_conv, W_self (4096 floats each) coalesced
    for (int i = t; i < 1024; i += 256) {
        ((float4*)sWc)[i] = ((const float4*)Wc)[i];
        ((float4*)sWs)[i] = ((const float4*)Ws)[i];
    }
    const int row0 = blockIdx.x * 64;
    int nrows = n - row0; if (nrows > 64) nrows = 64;
    for (int i = t; i < nrows * 16; i += 256) {
        ((float4*)sx)[i] = ((const float4*)(x + (long long)row0 * 64))[i];
    }
    __syncthreads();

    const int d = t & 63;   // output dim
    const int g = t >> 6;   // row group (4 groups x 16 rows)

    // pull this lane's W columns into registers (fully static indexing)
    float wcr[64], wsr[64];
#pragma unroll
    for (int k = 0; k < 64; ++k) { wcr[k] = sWc[k * 64 + d]; wsr[k] = sWs[k * 64 + d]; }

    const float bcd = bc[d], bsd = bs[d];

    for (int rr = g * 16; rr < (g + 1) * 16; ++rr) {
        if (rr >= nrows) break;
        float accC = 0.f, accS = 0.f;
#pragma unroll
        for (int k = 0; k < 64; ++k) {
            float xv = sx[rr * 64 + k];   // broadcast read (all lanes same addr)
            accC += xv * wcr[k];
            accS += xv * wsr[k];
        }
        const int r = row0 + rr;
        const float di = rsqrtf((float)deg[r]);
        if (d == 0) dinv[r] = di;
        const float yv = accC * di;
        y[(long long)r * 64 + d] = yv;
        out[(long long)r * 64 + d] = accS + bsd + bcd + di * yv;
    }
}

// ---------------- edge scatter: out[col] += dinv[col] * y[row] ----------------
// 16 threads per edge, each handles 4 dims via float4 gather + 4 f32 atomics.
__global__ __launch_bounds__(256) void k_scatter(
    const int* __restrict__ row, const int* __restrict__ col,
    const float* __restrict__ dinv, const float* __restrict__ y,
    float* __restrict__ out, int e)
{
    int idx = blockIdx.x * blockDim.x + threadIdx.x;
    int eidx = idx >> 4;
    if (eidx >= e) return;
    int j = idx & 15;
    int r = row[eidx];
    int c = col[eidx];
    float s = dinv[c];
    float4 v = ((const float4*)y)[(long long)r * 16 + j];
    float* o = out + (long long)c * 64 + (j << 2);
    unsafeAtomicAdd(o + 0, s * v.x);
    unsafeAtomicAdd(o + 1, s * v.y);
    unsafeAtomicAdd(o + 2, s * v.z);
    unsafeAtomicAdd(o + 3, s * v.w);
}

extern "C" void kernel_launch(void* const* d_in, const int* in_sizes, int n_in,
                              void* d_out, int out_size, void* d_ws, size_t ws_size,
                              hipStream_t stream) {
    const float* x  = (const float*)d_in[0];
    const int*   ei = (const int*)d_in[1];
    const float* Wc = (const float*)d_in[2];
    const float* bc = (const float*)d_in[3];
    const float* Ws = (const float*)d_in[4];
    const float* bs = (const float*)d_in[5];
    float* out = (float*)d_out;

    const int n = in_sizes[0] / 64;   // nodes
    const int e = in_sizes[1] / 2;    // directed edges
    const int* rowi = ei;             // sources
    const int* coli = ei + e;         // targets

    // workspace carve-up (256B-aligned slots): deg[n] int, dinv[n] f32, y[n*64] f32
    char* ws = (char*)d_ws;
    size_t off0 = 0;
    size_t off1 = (off0 + (size_t)n * 4 + 255) & ~(size_t)255;
    size_t off2 = (off1 + (size_t)n * 4 + 255) & ~(size_t)255;
    int*   deg  = (int*)(ws + off0);
    float* dinv = (float*)(ws + off1);
    float* y    = (float*)(ws + off2);

    k_deg_init<<<(n + 255) / 256, 256, 0, stream>>>(deg, n);
    k_deg_count<<<(e + 255) / 256, 256, 0, stream>>>(coli, deg, e);
    k_gemm<<<(n + 63) / 64, 256, 0, stream>>>(x, Wc, bc, Ws, bs, deg, dinv, y, out, n);

    long long total = (long long)e * 16;
    int blocks = (int)((total + 255) / 256);
    k_scatter<<<blocks, 256, 0, stream>>>(rowi, coli, dinv, y, out, e);
}

// Round 2
// 398.621 us; speedup vs baseline: 3.6826x; 3.6826x over previous
//
#include <hip/hip_runtime.h>

// ---------------- deg init: deg[i] = 1 (self-loop) ----------------
__global__ void k_deg_init(int* __restrict__ deg, int n) {
    int i = blockIdx.x * blockDim.x + threadIdx.x;
    if (i < n) deg[i] = 1;
}

// ---------------- deg count: deg[col[e]] += 1 ----------------
__global__ void k_deg_count(const int* __restrict__ col, int* __restrict__ deg, int e) {
    int i = blockIdx.x * blockDim.x + threadIdx.x;
    if (i < e) atomicAdd(&deg[col[i]], 1);
}

// ---------------- scan step 1: per-1024-block exclusive scan of (deg-1) ----------------
__global__ __launch_bounds__(1024) void k_scan1(const int* __restrict__ deg,
                                                int* __restrict__ offsets,
                                                int* __restrict__ bsum, int n) {
    __shared__ int s[1024];
    const int t = threadIdx.x;
    const int i = blockIdx.x * 1024 + t;
    int v = (i < n) ? (deg[i] - 1) : 0;   // edge in-degree (deg includes self-loop)
    s[t] = v;
    __syncthreads();
    for (int off = 1; off < 1024; off <<= 1) {
        int u = (t >= off) ? s[t - off] : 0;
        __syncthreads();
        s[t] += u;
        __syncthreads();
    }
    if (i < n) offsets[i] = s[t] - v;     // exclusive
    if (t == 1023) bsum[blockIdx.x] = s[t];
}

// ---------------- scan step 2: exclusive scan of block sums (single thread, nb<=128) ----
__global__ void k_scan2(int* __restrict__ bsum, int nb) {
    if (threadIdx.x == 0 && blockIdx.x == 0) {
        int run = 0;
        for (int j = 0; j < nb; ++j) { int v = bsum[j]; bsum[j] = run; run += v; }
    }
}

// ---------------- scan step 3: add block offsets, init cursor ----------------
__global__ void k_scan3(int* __restrict__ offsets, const int* __restrict__ bsum,
                        int* __restrict__ cursor, int n, int e) {
    int i = blockIdx.x * blockDim.x + threadIdx.x;
    if (i < n) {
        int o = offsets[i] + bsum[i >> 10];
        offsets[i] = o;
        cursor[i] = o;
    }
    if (i == 0) offsets[n] = e;
}

// ---------------- fill CSR buckets: bucket[slot] = row ----------------
__global__ void k_fill(const int* __restrict__ row, const int* __restrict__ col,
                       int* __restrict__ cursor, int* __restrict__ bucket, int e) {
    int i = blockIdx.x * blockDim.x + threadIdx.x;
    if (i < e) {
        int pos = atomicAdd(&cursor[col[i]], 1);
        bucket[pos] = row[i];
    }
}

// ---------------- fused dual GEMM + dinv + self-loop/bias init ----------------
__global__ __launch_bounds__(256) void k_gemm(
    const float* __restrict__ x, const float* __restrict__ Wc,
    const float* __restrict__ bc, const float* __restrict__ Ws,
    const float* __restrict__ bs, const int* __restrict__ deg,
    float* __restrict__ dinv, float* __restrict__ y,
    float* __restrict__ out, int n)
{
    __shared__ float sWc[64 * 64];
    __shared__ float sWs[64 * 64];
    __shared__ float sx[64 * 64];
    const int t = threadIdx.x;

    for (int i = t; i < 1024; i += 256) {
        ((float4*)sWc)[i] = ((const float4*)Wc)[i];
        ((float4*)sWs)[i] = ((const float4*)Ws)[i];
    }
    const int row0 = blockIdx.x * 64;
    int nrows = n - row0; if (nrows > 64) nrows = 64;
    for (int i = t; i < nrows * 16; i += 256) {
        ((float4*)sx)[i] = ((const float4*)(x + (long long)row0 * 64))[i];
    }
    __syncthreads();

    const int d = t & 63;
    const int g = t >> 6;

    float wcr[64], wsr[64];
#pragma unroll
    for (int k = 0; k < 64; ++k) { wcr[k] = sWc[k * 64 + d]; wsr[k] = sWs[k * 64 + d]; }

    const float bcd = bc[d], bsd = bs[d];

    for (int rr = g * 16; rr < (g + 1) * 16; ++rr) {
        if (rr >= nrows) break;
        float accC = 0.f, accS = 0.f;
#pragma unroll
        for (int k = 0; k < 64; ++k) {
            float xv = sx[rr * 64 + k];
            accC += xv * wcr[k];
            accS += xv * wsr[k];
        }
        const int r = row0 + rr;
        const float di = rsqrtf((float)deg[r]);
        if (d == 0) dinv[r] = di;
        const float yv = accC * di;
        y[(long long)r * 64 + d] = yv;
        out[(long long)r * 64 + d] = accS + bsd + bcd + di * yv;
    }
}

// ---------------- gather: one 64-lane wave per node, no atomics ----------------
__global__ __launch_bounds__(256) void k_gather(
    const int* __restrict__ offsets, const int* __restrict__ bucket,
    const float* __restrict__ dinv, const float* __restrict__ y,
    float* __restrict__ out, int n)
{
    const int node = blockIdx.x * 4 + (threadIdx.x >> 6);
    if (node >= n) return;
    const int d = threadIdx.x & 63;
    const int beg = offsets[node];
    const int end = offsets[node + 1];
    float acc = 0.f;
    for (int k = beg; k < end; ++k) {
        int r = bucket[k];                      // wave-uniform
        acc += y[(long long)r * 64 + d];        // coalesced 256B per edge
    }
    if (end > beg) {
        long long o = (long long)node * 64 + d;
        out[o] += dinv[node] * acc;
    }
}

// ---------------- fallback atomic scatter (if ws too small for CSR) ----------------
__global__ __launch_bounds__(256) void k_scatter(
    const int* __restrict__ row, const int* __restrict__ col,
    const float* __restrict__ dinv, const float* __restrict__ y,
    float* __restrict__ out, int e)
{
    int idx = blockIdx.x * blockDim.x + threadIdx.x;
    int eidx = idx >> 4;
    if (eidx >= e) return;
    int j = idx & 15;
    int r = row[eidx];
    int c = col[eidx];
    float s = dinv[c];
    float4 v = ((const float4*)y)[(long long)r * 16 + j];
    float* o = out + (long long)c * 64 + (j << 2);
    unsafeAtomicAdd(o + 0, s * v.x);
    unsafeAtomicAdd(o + 1, s * v.y);
    unsafeAtomicAdd(o + 2, s * v.z);
    unsafeAtomicAdd(o + 3, s * v.w);
}

extern "C" void kernel_launch(void* const* d_in, const int* in_sizes, int n_in,
                              void* d_out, int out_size, void* d_ws, size_t ws_size,
                              hipStream_t stream) {
    const float* x  = (const float*)d_in[0];
    const int*   ei = (const int*)d_in[1];
    const float* Wc = (const float*)d_in[2];
    const float* bc = (const float*)d_in[3];
    const float* Ws = (const float*)d_in[4];
    const float* bs = (const float*)d_in[5];
    float* out = (float*)d_out;

    const int n = in_sizes[0] / 64;   // nodes
    const int e = in_sizes[1] / 2;    // directed edges
    const int* rowi = ei;             // sources
    const int* coli = ei + e;         // targets

    // workspace carve-up (256B-aligned): deg, dinv, y, offsets, cursor, bucket, bsum
    auto align = [](size_t v) { return (v + 255) & ~(size_t)255; };
    const int nb = (n + 1023) / 1024;
    size_t o_deg  = 0;
    size_t o_dinv = align(o_deg  + (size_t)n * 4);
    size_t o_y    = align(o_dinv + (size_t)n * 4);
    size_t o_off  = align(o_y    + (size_t)n * 256);
    size_t o_cur  = align(o_off  + (size_t)(n + 1) * 4);
    size_t o_bkt  = align(o_cur  + (size_t)n * 4);
    size_t o_bsum = align(o_bkt  + (size_t)e * 4);
    size_t total  = o_bsum + (size_t)nb * 4;

    char* ws = (char*)d_ws;
    int*   deg  = (int*)(ws + o_deg);
    float* dinv = (float*)(ws + o_dinv);
    float* y    = (float*)(ws + o_y);

    k_deg_init<<<(n + 255) / 256, 256, 0, stream>>>(deg, n);
    k_deg_count<<<(e + 255) / 256, 256, 0, stream>>>(coli, deg, e);

    const bool csr_ok = (total <= ws_size);

    if (csr_ok) {
        int* offsets = (int*)(ws + o_off);
        int* cursor  = (int*)(ws + o_cur);
        int* bucket  = (int*)(ws + o_bkt);
        int* bsum    = (int*)(ws + o_bsum);

        k_scan1<<<nb, 1024, 0, stream>>>(deg, offsets, bsum, n);
        k_scan2<<<1, 64, 0, stream>>>(bsum, nb);
        k_scan3<<<(n + 255) / 256, 256, 0, stream>>>(offsets, bsum, cursor, n, e);
        k_gemm<<<(n + 63) / 64, 256, 0, stream>>>(x, Wc, bc, Ws, bs, deg, dinv, y, out, n);
        k_fill<<<(e + 255) / 256, 256, 0, stream>>>(rowi, coli, cursor, bucket, e);
        k_gather<<<(n + 3) / 4, 256, 0, stream>>>(offsets, bucket, dinv, y, out, n);
    } else {
        k_gemm<<<(n + 63) / 64, 256, 0, stream>>>(x, Wc, bc, Ws, bs, deg, dinv, y, out, n);
        long long tot = (long long)e * 16;
        k_scatter<<<(int)((tot + 255) / 256), 256, 0, stream>>>(rowi, coli, dinv, y, out, e);
    }
}

// Round 3
// 238.499 us; speedup vs baseline: 6.1550x; 1.6714x over previous
//
#include <hip/hip_runtime.h>

#define CAP 64

// ================= padded-bucket path =================

__global__ void k_init(int* __restrict__ cnt, int* __restrict__ ovf_cnt, int n) {
    int i = blockIdx.x * blockDim.x + threadIdx.x;
    if (i < n) cnt[i] = 0;
    if (i == 0) *ovf_cnt = 0;
}

__global__ void k_fill_pad(const int* __restrict__ row, const int* __restrict__ col,
                           int* __restrict__ cnt, int* __restrict__ bucket,
                           int* __restrict__ ovf, int* __restrict__ ovf_cnt, int e) {
    int i = blockIdx.x * blockDim.x + threadIdx.x;
    if (i >= e) return;
    int c = col[i];
    int p = atomicAdd(&cnt[c], 1);
    if (p < CAP) bucket[(size_t)c * CAP + p] = row[i];
    else { int q = atomicAdd(ovf_cnt, 1); ovf[q] = i; }
}

// gather: one 64-lane wave per node. Lane-parallel bucket load + shfl broadcast,
// 8-wide unrolled y-row loads with independent accumulators (MLP=8).
__global__ __launch_bounds__(256) void k_gather_pad(
    const int* __restrict__ cnt, const int* __restrict__ bucket,
    const float* __restrict__ y, float* __restrict__ out, int n)
{
    const int node = blockIdx.x * 4 + (threadIdx.x >> 6);
    if (node >= n) return;
    const int lane = threadIdx.x & 63;
    int m = cnt[node];
    const float di = rsqrtf((float)(m + 1));      // deg incl. self-loop
    if (m > CAP) m = CAP;                          // overflow handled separately
    if (m == 0) return;

    int rl = (lane < m) ? bucket[(size_t)node * CAP + lane] : 0;  // one coalesced load

    float a0=0.f,a1=0.f,a2=0.f,a3=0.f,a4=0.f,a5=0.f,a6=0.f,a7=0.f;
    int k = 0;
    for (; k + 8 <= m; k += 8) {
        int r0=__shfl(rl,k+0), r1=__shfl(rl,k+1), r2=__shfl(rl,k+2), r3=__shfl(rl,k+3);
        int r4=__shfl(rl,k+4), r5=__shfl(rl,k+5), r6=__shfl(rl,k+6), r7=__shfl(rl,k+7);
        a0 += y[(size_t)r0*64 + lane];
        a1 += y[(size_t)r1*64 + lane];
        a2 += y[(size_t)r2*64 + lane];
        a3 += y[(size_t)r3*64 + lane];
        a4 += y[(size_t)r4*64 + lane];
        a5 += y[(size_t)r5*64 + lane];
        a6 += y[(size_t)r6*64 + lane];
        a7 += y[(size_t)r7*64 + lane];
    }
    for (; k + 2 <= m; k += 2) {
        int r0=__shfl(rl,k+0), r1=__shfl(rl,k+1);
        a0 += y[(size_t)r0*64 + lane];
        a1 += y[(size_t)r1*64 + lane];
    }
    if (k < m) { int r0=__shfl(rl,k); a0 += y[(size_t)r0*64 + lane]; }

    float acc = ((a0+a1)+(a2+a3)) + ((a4+a5)+(a6+a7));
    out[(size_t)node*64 + lane] += di * acc;
}

// overflow edges (deg > CAP): atomic fallback, runs AFTER gather (no RMW race).
__global__ void k_ovf(const int* __restrict__ ovf_cnt, const int* __restrict__ ovf,
                      const int* __restrict__ row, const int* __restrict__ col,
                      const float* __restrict__ dinv, const float* __restrict__ y,
                      float* __restrict__ out) {
    int m = *ovf_cnt;
    long long total = (long long)m * 16;
    for (long long idx = blockIdx.x*blockDim.x+threadIdx.x; idx < total;
         idx += (long long)gridDim.x*blockDim.x) {
        int ei = ovf[idx >> 4];
        int j = (int)(idx & 15);
        int r = row[ei], c = col[ei];
        float s = dinv[c];
        float4 v = ((const float4*)y)[(size_t)r*16 + j];
        float* o = out + (size_t)c*64 + (j<<2);
        unsafeAtomicAdd(o+0, s*v.x);
        unsafeAtomicAdd(o+1, s*v.y);
        unsafeAtomicAdd(o+2, s*v.z);
        unsafeAtomicAdd(o+3, s*v.w);
    }
}

// ================= fused dual GEMM + dinv + self-loop/bias init =================
// add: deg[r]+add is the full degree (padded path stores edge count, add=1;
// CSR path stores deg incl. self-loop, add=0).
__global__ __launch_bounds__(256) void k_gemm(
    const float* __restrict__ x, const float* __restrict__ Wc,
    const float* __restrict__ bc, const float* __restrict__ Ws,
    const float* __restrict__ bs, const int* __restrict__ deg, int add,
    float* __restrict__ dinv, float* __restrict__ y,
    float* __restrict__ out, int n)
{
    __shared__ __align__(16) float sWc[64 * 64];
    __shared__ __align__(16) float sWs[64 * 64];
    __shared__ __align__(16) float sx[64 * 64];
    const int t = threadIdx.x;

    for (int i = t; i < 1024; i += 256) {
        ((float4*)sWc)[i] = ((const float4*)Wc)[i];
        ((float4*)sWs)[i] = ((const float4*)Ws)[i];
    }
    const int row0 = blockIdx.x * 64;
    int nrows = n - row0; if (nrows > 64) nrows = 64;
    for (int i = t; i < nrows * 16; i += 256) {
        ((float4*)sx)[i] = ((const float4*)(x + (size_t)row0 * 64))[i];
    }
    __syncthreads();

    const int d = t & 63;
    const int g = t >> 6;

    float wcr[64], wsr[64];
#pragma unroll
    for (int k = 0; k < 64; ++k) { wcr[k] = sWc[k * 64 + d]; wsr[k] = sWs[k * 64 + d]; }

    const float bcd = bc[d], bsd = bs[d];

    for (int rr = g * 16; rr < (g + 1) * 16; ++rr) {
        if (rr >= nrows) break;
        float accC = 0.f, accS = 0.f;
        const float4* xv4 = (const float4*)(sx + rr * 64);
#pragma unroll
        for (int q = 0; q < 16; ++q) {
            float4 xv = xv4[q];          // broadcast b128 read
            accC += xv.x*wcr[4*q+0] + xv.y*wcr[4*q+1] + xv.z*wcr[4*q+2] + xv.w*wcr[4*q+3];
            accS += xv.x*wsr[4*q+0] + xv.y*wsr[4*q+1] + xv.z*wsr[4*q+2] + xv.w*wsr[4*q+3];
        }
        const int r = row0 + rr;
        const float di = rsqrtf((float)(deg[r] + add));
        if (d == 0) dinv[r] = di;
        const float yv = accC * di;
        y[(size_t)r * 64 + d] = yv;
        out[(size_t)r * 64 + d] = accS + bsd + bcd + di * yv;
    }
}

// ================= CSR fallback path (round-2 proven) =================

__global__ void k_deg_init(int* __restrict__ deg, int n) {
    int i = blockIdx.x * blockDim.x + threadIdx.x;
    if (i < n) deg[i] = 1;
}

__global__ void k_deg_count(const int* __restrict__ col, int* __restrict__ deg, int e) {
    int i = blockIdx.x * blockDim.x + threadIdx.x;
    if (i < e) atomicAdd(&deg[col[i]], 1);
}

__global__ __launch_bounds__(1024) void k_scan1(const int* __restrict__ deg,
                                                int* __restrict__ offsets,
                                                int* __restrict__ bsum, int n) {
    __shared__ int s[1024];
    const int t = threadIdx.x;
    const int i = blockIdx.x * 1024 + t;
    int v = (i < n) ? (deg[i] - 1) : 0;
    s[t] = v;
    __syncthreads();
    for (int off = 1; off < 1024; off <<= 1) {
        int u = (t >= off) ? s[t - off] : 0;
        __syncthreads();
        s[t] += u;
        __syncthreads();
    }
    if (i < n) offsets[i] = s[t] - v;
    if (t == 1023) bsum[blockIdx.x] = s[t];
}

__global__ void k_scan2(int* __restrict__ bsum, int nb) {
    if (threadIdx.x == 0 && blockIdx.x == 0) {
        int run = 0;
        for (int j = 0; j < nb; ++j) { int v = bsum[j]; bsum[j] = run; run += v; }
    }
}

__global__ void k_scan3(int* __restrict__ offsets, const int* __restrict__ bsum,
                        int* __restrict__ cursor, int n, int e) {
    int i = blockIdx.x * blockDim.x + threadIdx.x;
    if (i < n) {
        int o = offsets[i] + bsum[i >> 10];
        offsets[i] = o;
        cursor[i] = o;
    }
    if (i == 0) offsets[n] = e;
}

__global__ void k_fill(const int* __restrict__ row, const int* __restrict__ col,
                       int* __restrict__ cursor, int* __restrict__ bucket, int e) {
    int i = blockIdx.x * blockDim.x + threadIdx.x;
    if (i < e) {
        int pos = atomicAdd(&cursor[col[i]], 1);
        bucket[pos] = row[i];
    }
}

__global__ __launch_bounds__(256) void k_gather(
    const int* __restrict__ offsets, const int* __restrict__ bucket,
    const float* __restrict__ dinv, const float* __restrict__ y,
    float* __restrict__ out, int n)
{
    const int node = blockIdx.x * 4 + (threadIdx.x >> 6);
    if (node >= n) return;
    const int d = threadIdx.x & 63;
    const int beg = offsets[node];
    const int end = offsets[node + 1];
    float acc = 0.f;
    for (int k = beg; k < end; ++k) {
        int r = bucket[k];
        acc += y[(size_t)r * 64 + d];
    }
    if (end > beg) out[(size_t)node * 64 + d] += dinv[node] * acc;
}

__global__ __launch_bounds__(256) void k_scatter(
    const int* __restrict__ row, const int* __restrict__ col,
    const float* __restrict__ dinv, const float* __restrict__ y,
    float* __restrict__ out, int e)
{
    int idx = blockIdx.x * blockDim.x + threadIdx.x;
    int eidx = idx >> 4;
    if (eidx >= e) return;
    int j = idx & 15;
    int r = row[eidx];
    int c = col[eidx];
    float s = dinv[c];
    float4 v = ((const float4*)y)[(size_t)r * 16 + j];
    float* o = out + (size_t)c * 64 + (j << 2);
    unsafeAtomicAdd(o + 0, s * v.x);
    unsafeAtomicAdd(o + 1, s * v.y);
    unsafeAtomicAdd(o + 2, s * v.z);
    unsafeAtomicAdd(o + 3, s * v.w);
}

extern "C" void kernel_launch(void* const* d_in, const int* in_sizes, int n_in,
                              void* d_out, int out_size, void* d_ws, size_t ws_size,
                              hipStream_t stream) {
    const float* x  = (const float*)d_in[0];
    const int*   ei = (const int*)d_in[1];
    const float* Wc = (const float*)d_in[2];
    const float* bc = (const float*)d_in[3];
    const float* Ws = (const float*)d_in[4];
    const float* bs = (const float*)d_in[5];
    float* out = (float*)d_out;

    const int n = in_sizes[0] / 64;
    const int e = in_sizes[1] / 2;
    const int* rowi = ei;
    const int* coli = ei + e;

    auto align = [](size_t v) { return (v + 255) & ~(size_t)255; };
    char* ws = (char*)d_ws;

    // ---- padded-bucket layout ----
    size_t p_cnt  = 0;
    size_t p_dinv = align(p_cnt  + (size_t)n * 4);
    size_t p_y    = align(p_dinv + (size_t)n * 4);
    size_t p_bkt  = align(p_y    + (size_t)n * 256);
    size_t p_ovf  = align(p_bkt  + (size_t)n * CAP * 4);
    size_t p_ovfc = align(p_ovf  + (size_t)e * 4);
    size_t p_tot  = p_ovfc + 256;

    // ---- CSR layout ----
    const int nb = (n + 1023) / 1024;
    size_t c_deg  = 0;
    size_t c_dinv = align(c_deg  + (size_t)n * 4);
    size_t c_y    = align(c_dinv + (size_t)n * 4);
    size_t c_off  = align(c_y    + (size_t)n * 256);
    size_t c_cur  = align(c_off  + (size_t)(n + 1) * 4);
    size_t c_bkt  = align(c_cur  + (size_t)n * 4);
    size_t c_bsum = align(c_bkt  + (size_t)e * 4);
    size_t c_tot  = c_bsum + (size_t)nb * 4;

    if (p_tot <= ws_size) {
        int*   cnt    = (int*)(ws + p_cnt);
        float* dinv   = (float*)(ws + p_dinv);
        float* y      = (float*)(ws + p_y);
        int*   bucket = (int*)(ws + p_bkt);
        int*   ovf    = (int*)(ws + p_ovf);
        int*   ovfc   = (int*)(ws + p_ovfc);

        k_init<<<(n + 255) / 256, 256, 0, stream>>>(cnt, ovfc, n);
        k_fill_pad<<<(e + 255) / 256, 256, 0, stream>>>(rowi, coli, cnt, bucket, ovf, ovfc, e);
        k_gemm<<<(n + 63) / 64, 256, 0, stream>>>(x, Wc, bc, Ws, bs, cnt, 1, dinv, y, out, n);
        k_gather_pad<<<(n + 3) / 4, 256, 0, stream>>>(cnt, bucket, y, out, n);
        k_ovf<<<64, 256, 0, stream>>>(ovfc, ovf, rowi, coli, dinv, y, out);
    } else if (c_tot <= ws_size) {
        int*   deg     = (int*)(ws + c_deg);
        float* dinv    = (float*)(ws + c_dinv);
        float* y       = (float*)(ws + c_y);
        int*   offsets = (int*)(ws + c_off);
        int*   cursor  = (int*)(ws + c_cur);
        int*   bucket  = (int*)(ws + c_bkt);
        int*   bsum    = (int*)(ws + c_bsum);

        k_deg_init<<<(n + 255) / 256, 256, 0, stream>>>(deg, n);
        k_deg_count<<<(e + 255) / 256, 256, 0, stream>>>(coli, deg, e);
        k_scan1<<<nb, 1024, 0, stream>>>(deg, offsets, bsum, n);
        k_scan2<<<1, 64, 0, stream>>>(bsum, nb);
        k_scan3<<<(n + 255) / 256, 256, 0, stream>>>(offsets, bsum, cursor, n, e);
        k_gemm<<<(n + 63) / 64, 256, 0, stream>>>(x, Wc, bc, Ws, bs, deg, 0, dinv, y, out, n);
        k_fill<<<(e + 255) / 256, 256, 0, stream>>>(rowi, coli, cursor, bucket, e);
        k_gather<<<(n + 3) / 4, 256, 0, stream>>>(offsets, bucket, dinv, y, out, n);
    } else {
        int*   deg  = (int*)(ws + c_deg);
        float* dinv = (float*)(ws + c_dinv);
        float* y    = (float*)(ws + c_y);
        k_deg_init<<<(n + 255) / 256, 256, 0, stream>>>(deg, n);
        k_deg_count<<<(e + 255) / 256, 256, 0, stream>>>(coli, deg, e);
        k_gemm<<<(n + 63) / 64, 256, 0, stream>>>(x, Wc, bc, Ws, bs, deg, 0, dinv, y, out, n);
        long long tot = (long long)e * 16;
        k_scatter<<<(int)((tot + 255) / 256), 256, 0, stream>>>(rowi, coli, dinv, y, out, e);
    }
}